// Round 3
// baseline (240.135 us; speedup 1.0000x reference)
//
#include <hip/hip_runtime.h>
#include <stdint.h>

// 3x3 conv s1 p1, NCHW fp32, 64->128 ch, 16x112x112.
// Implicit GEMM on bf16 MFMA with NHWC bf16 x-repack in d_ws:
//   prep:  x (NCHW fp32) -> x_t[(n*12544+p)*64+ic] bf16 ; w -> Wt[tap][oc][ic] bf16 ; 128B zero block
//   conv:  per block 128oc x 128px tile. Taps grouped by dy (3 groups of 3 dx-taps).
//          X: per-dy window (130 pixel rows + zero row, 16.4KB) double-buffered in LDS,
//             staged via global_load_lds w/ source-side XOR swizzle; THREE barriers total.
//          W: NO LDS - per-lane 16B global loads (147KB tensor is L1/L2-resident broadcast);
//             issued at tap start, covered by ds_read+MFMA interleave + 16-wave TLP.
//          LDS 33.5KB + VGPR<=128 => 4 blocks/CU. XCD-chunked block swizzle for L2 locality
//          (per-XCD xt working set 3.2MB < 4MB L2).
//          Boundary pixels: b-frag row cndmask'd to the zero row (tap-dependent, cheap VALU).

#define HW     112
#define PIX    12544
#define ICN    64
#define OCN    128
#define TILEP  128
#define PTILES 98
#define NBLK   1568
#define NIMG   16

#define XT_BYTES   (NIMG * PIX * ICN * 2)          // 25,690,112
#define WT_OFF     XT_BYTES
#define WT_BYTES   (9 * OCN * ICN * 2)             // 147,456
#define ZG_OFF     (WT_OFF + WT_BYTES)             // 128B zero block
#define XBLK       (NIMG * (PIX / 64))             // 3136 transpose blocks
#define WBLK       72                              // 72 * 1024 = 73728 weight elems

#define XW_ZROW    130                             // zero row index in window
#define XW_BYTES   (131 * 128)                     // 16,768 per buffer

typedef __attribute__((ext_vector_type(8))) __bf16 bf16x8;
typedef __attribute__((ext_vector_type(4))) float  f32x4;

__device__ __forceinline__ uint32_t rne_lo(float f) {
    uint32_t u = __builtin_bit_cast(uint32_t, f);
    return (u + 0x7fffu + ((u >> 16) & 1u)) >> 16;
}
__device__ __forceinline__ uint32_t pk2(float a, float b) {
    uint32_t ub = __builtin_bit_cast(uint32_t, b);
    ub = (ub + 0x7fffu + ((ub >> 16) & 1u)) & 0xffff0000u;
    return rne_lo(a) | ub;
}

__device__ __forceinline__ void load_lds16(const void* g, void* l) {
    __builtin_amdgcn_global_load_lds(
        (const __attribute__((address_space(1))) uint32_t*)g,
        (__attribute__((address_space(3))) uint32_t*)l, 16, 0, 0);
}

// ---------------- prep: x transpose+cvt, weight transpose+cvt, zero block ----------------
__global__ void __launch_bounds__(256)
prep(const float* __restrict__ x, const float* __restrict__ w, uint8_t* __restrict__ ws) {
    const int b = blockIdx.x;
    const int t = threadIdx.x;
    uint16_t* xt = (uint16_t*)ws;
    uint16_t* wt = (uint16_t*)(ws + WT_OFF);

    if (b < XBLK) {
        // 64 pixels per block; thread: pixel = t>>2, ic chunk q = t&3 (16 ic each)
        const int n  = b / (PIX / 64);
        const int p0 = (b - n * (PIX / 64)) * 64;
        const int px = t >> 2;
        const int q  = t & 3;
        const float* src = x + ((size_t)n * ICN + q * 16) * PIX + p0 + px;
        float v[16];
#pragma unroll
        for (int i = 0; i < 16; ++i) v[i] = src[(size_t)i * PIX];
        uint4 u0 = make_uint4(pk2(v[0], v[1]),  pk2(v[2], v[3]),
                              pk2(v[4], v[5]),  pk2(v[6], v[7]));
        uint4 u1 = make_uint4(pk2(v[8], v[9]),  pk2(v[10], v[11]),
                              pk2(v[12], v[13]), pk2(v[14], v[15]));
        char* dst = (char*)xt + ((size_t)(n * PIX + p0 + px)) * 128 + q * 32;
        *(uint4*)dst        = u0;
        *(uint4*)(dst + 16) = u1;
    } else {
        const int wb = b - XBLK;
#pragma unroll
        for (int k = 0; k < 4; ++k) {
            int wi = wb * 1024 + k * 256 + t;          // [0, 73728)
            int r  = wi >> 13;
            int oc = (wi >> 6) & 127;
            int ic = wi & 63;
            wt[wi] = (uint16_t)rne_lo(w[oc * 576 + ic * 9 + r]);
        }
        if (wb == 0 && t < 8) ((uint4*)(ws + ZG_OFF))[t] = make_uint4(0, 0, 0, 0);
    }
}

// ---------------- main conv ----------------
__global__ void __launch_bounds__(256, 4)
conv_mfma(const uint8_t* __restrict__ ws, const float* __restrict__ bias,
          float* __restrict__ out) {
    __shared__ __align__(1024) uint8_t Xw[2][XW_BYTES];   // per-dy X window, double-buffered

    const char* xt = (const char*)ws;
    const char* wt = (const char*)(ws + WT_OFF);
    const char* zg = (const char*)(ws + ZG_OFF);

    const int t = threadIdx.x;
    // XCD-chunked bijective swizzle (1568 = 8*196): consecutive work ids share an XCD.
    const int b = (blockIdx.x & 7) * (NBLK / 8) + (blockIdx.x >> 3);
    const int n_img = b / PTILES;
    const int p0 = (b - n_img * PTILES) * TILEP;

    const int lane = t & 63;
    const int wave = t >> 6;
    const int lr = lane & 15;
    const int lq = lane >> 4;
    const int oc_base = (wave & 1) * 64;
    const int px_base = (wave >> 1) * 64;

    // ---- staging geometry: pass covers 32 rows; row = pass*32 + (t>>3); chunk = t&7 ----
    // Source-side XOR swizzle (LDS dest linear): LDS[row][slot] = chunk slot^(row&7).
    const int rowB  = t >> 3;                        // 0..31 ; row&7 == rowB&7
    const int cswz8 = ((t & 7) ^ (rowB & 7)) * 16;
    const char* zaddr = zg + (t & 7) * 16;
    const char* xsrc  = xt + ((ptrdiff_t)n_img * PIX) * 128 + cswz8;   // + pw*128

    // ---- per-ni pixel geometry; window row = (p - p0) + dx + 1 (dy-independent) ----
    int hh[4], wwp[4], rbase[4];
#pragma unroll
    for (int ni = 0; ni < 4; ++ni) {
        int po = px_base + ni * 16 + lr;
        int p  = p0 + po;
        int h  = p / HW;
        hh[ni]  = h;
        wwp[ni] = p - h * HW;
        rbase[ni] = po + 1;
    }
    // ---- per-mi weight byte offsets (lq chunk folded in; + tap*16384 + kh*64 at use) ----
    int woff[4];
#pragma unroll
    for (int mi = 0; mi < 4; ++mi)
        woff[mi] = (oc_base + mi * 16 + lr) * 128 + lq * 16;

    // ---- zero rows of both buffers ----
    if (t < 16)
        *(uint4*)(&Xw[t >> 3][XW_ZROW * 128 + (t & 7) * 16]) = make_uint4(0, 0, 0, 0);

    // ---- stage group 0 window (dy=-1): rows 0..129 hold pixel p0-113+row ----
    {
        const int pb = p0 - 113;
#pragma unroll
        for (int r2 = 0; r2 < 5; ++r2) {
            if (r2 < 4 || rowB < 2) {                 // rows 0..129 only
                int pw = pb + r2 * 32 + rowB;
                const char* gp = ((unsigned)pw < PIX) ? (xsrc + (ptrdiff_t)pw * 128) : zaddr;
                load_lds16(gp, (char*)Xw[0] + r2 * 4096 + wave * 1024);
            }
        }
    }

    f32x4 acc[4][4];
    {
        f32x4 z = {0.f, 0.f, 0.f, 0.f};
#pragma unroll
        for (int i = 0; i < 4; ++i)
#pragma unroll
            for (int j = 0; j < 4; ++j) acc[i][j] = z;
    }

    __syncthreads();   // group-0 window staged (vmcnt(0)+lgkmcnt(0)+barrier)

#pragma unroll
    for (int g = 0; g < 3; ++g) {
        const int dy = g - 1;

        // stage next group's window into the other buffer; drained by group-end barrier,
        // fully covered by this group's 3-tap compute (~96 MFMA + 24 ds_read).
        if (g < 2) {
            const int pb = p0 + (dy + 1) * HW - 1;
#pragma unroll
            for (int r2 = 0; r2 < 5; ++r2) {
                if (r2 < 4 || rowB < 2) {
                    int pw = pb + r2 * 32 + rowB;
                    const char* gp = ((unsigned)pw < PIX) ? (xsrc + (ptrdiff_t)pw * 128) : zaddr;
                    load_lds16(gp, (char*)Xw[(g + 1) & 1] + r2 * 4096 + wave * 1024);
                }
            }
        }

        const char* xb = (const char*)Xw[g & 1];

#pragma unroll
        for (int dxi = 0; dxi < 3; ++dxi) {
            const int dx  = dxi - 1;
            const int tap = g * 3 + dxi;

            // A-fragments straight from global (L1-resident broadcast): 8 x 16B per lane.
            bf16x8 a0[4], a1[4];
#pragma unroll
            for (int mi = 0; mi < 4; ++mi) {
                const char* wa = wt + tap * 16384 + woff[mi];
                a0[mi] = *(const bf16x8*)(wa);
                a1[mi] = *(const bf16x8*)(wa + 64);
            }

            // boundary: redirect invalid rows to the zero row
            int ro[4];
#pragma unroll
            for (int ni = 0; ni < 4; ++ni) {
                bool ok = ((unsigned)(hh[ni] + dy) < HW) & ((unsigned)(wwp[ni] + dx) < HW);
                ro[ni] = ok ? (rbase[ni] + dx) : XW_ZROW;
            }

            // ---- kh = 0 ----
            {
                bf16x8 b0[4];
#pragma unroll
                for (int ni = 0; ni < 4; ++ni)
                    b0[ni] = *(const bf16x8*)(xb + ro[ni] * 128 + ((lq ^ (ro[ni] & 7)) * 16));
#pragma unroll
                for (int mi = 0; mi < 4; ++mi)
#pragma unroll
                    for (int ni = 0; ni < 4; ++ni)
                        acc[mi][ni] = __builtin_amdgcn_mfma_f32_16x16x32_bf16(
                            a0[mi], b0[ni], acc[mi][ni], 0, 0, 0);
            }
            // ---- kh = 1 ----
            {
                bf16x8 b1[4];
#pragma unroll
                for (int ni = 0; ni < 4; ++ni)
                    b1[ni] = *(const bf16x8*)(xb + ro[ni] * 128 + (((4 + lq) ^ (ro[ni] & 7)) * 16));
#pragma unroll
                for (int mi = 0; mi < 4; ++mi)
#pragma unroll
                    for (int ni = 0; ni < 4; ++ni)
                        acc[mi][ni] = __builtin_amdgcn_mfma_f32_16x16x32_bf16(
                            a1[mi], b1[ni], acc[mi][ni], 0, 0, 0);
            }
        }

        if (g < 2) __syncthreads();   // drains next-window stage + releases buffer swap
    }

    // ---- epilogue: D col = lane&15 -> pixel, row = lq*4+reg -> oc (validated R1)
#pragma unroll
    for (int mi = 0; mi < 4; ++mi) {
#pragma unroll
        for (int rg = 0; rg < 4; ++rg) {
            const int oc = oc_base + mi * 16 + lq * 4 + rg;
            const float bb = bias[oc];
            float* orow = out + ((size_t)n_img * OCN + oc) * PIX + p0 + px_base + lr;
#pragma unroll
            for (int ni = 0; ni < 4; ++ni)
                orow[ni * 16] = acc[mi][ni][rg] + bb;
        }
    }
}

extern "C" void kernel_launch(void* const* d_in, const int* in_sizes, int n_in,
                              void* d_out, int out_size, void* d_ws, size_t ws_size,
                              hipStream_t stream) {
    const float* x    = (const float*)d_in[0];
    const float* w    = (const float*)d_in[1];
    const float* bias = (const float*)d_in[2];
    float* out = (float*)d_out;
    uint8_t* ws = (uint8_t*)d_ws;   // needs ZG_OFF + 128 = 25,837,696 bytes

    prep<<<XBLK + WBLK, 256, 0, stream>>>(x, w, ws);
    conv_mfma<<<NBLK, 256, 0, stream>>>(ws, bias, out);
}

// Round 4
// 171.300 us; speedup vs baseline: 1.4018x; 1.4018x over previous
//
#include <hip/hip_runtime.h>
#include <stdint.h>

// 3x3 conv s1 p1, NCHW fp32, 64->128 ch, 16x112x112.
// Implicit GEMM on bf16 MFMA with NHWC bf16 x-repack in d_ws:
//   prep:  x (NCHW fp32) -> x_t[(n*12544+p)*64+ic] bf16 ; w -> Wt[tap][oc][ic] bf16 ; 128B zero block
//   conv:  per block 128oc x 128px tile; 9 taps, per tap stage As(16KB)+Xs(16KB) via
//          global_load_lds width=16 (XOR-swizzled chunks), 32 MFMA (16x16x32 bf16).
// Boundary pixels: per-lane global address redirected to the zero block (no LDS patching).
// R4: + bijective XCD-chunked block swizzle (1568 = 8*196). Each XCD's chunk covers 2 images
//     -> 3.2MB xt slice resident in the 4MB per-XCD L2, so the 9x per-tap restage drains at
//     L2 latency instead of L3. (R1-R3 established: all-LDS operand feed + max occupancy is
//     the right structure; this attacks the remaining barrier-drain latency term.)

#define HW     112
#define PIX    12544
#define ICN    64
#define OCN    128
#define TILEP  128
#define PTILES 98
#define NBLK   1568
#define NIMG   16

#define XT_BYTES   (NIMG * PIX * ICN * 2)          // 25,690,112
#define WT_OFF     XT_BYTES
#define WT_BYTES   (9 * OCN * ICN * 2)             // 147,456
#define ZG_OFF     (WT_OFF + WT_BYTES)             // 128B zero block
#define XBLK       (NIMG * (PIX / 64))             // 3136 transpose blocks
#define WBLK       72                              // 72 * 1024 = 73728 weight elems

typedef __attribute__((ext_vector_type(8))) __bf16 bf16x8;
typedef __attribute__((ext_vector_type(4))) float  f32x4;

__device__ __forceinline__ uint32_t rne_lo(float f) {
    uint32_t u = __builtin_bit_cast(uint32_t, f);
    return (u + 0x7fffu + ((u >> 16) & 1u)) >> 16;
}
__device__ __forceinline__ uint32_t pk2(float a, float b) {
    uint32_t ub = __builtin_bit_cast(uint32_t, b);
    ub = (ub + 0x7fffu + ((ub >> 16) & 1u)) & 0xffff0000u;
    return rne_lo(a) | ub;
}

__device__ __forceinline__ void load_lds16(const void* g, void* l) {
    __builtin_amdgcn_global_load_lds(
        (const __attribute__((address_space(1))) uint32_t*)g,
        (__attribute__((address_space(3))) uint32_t*)l, 16, 0, 0);
}

// ---------------- prep: x transpose+cvt, weight transpose+cvt, zero block ----------------
__global__ void __launch_bounds__(256)
prep(const float* __restrict__ x, const float* __restrict__ w, uint8_t* __restrict__ ws) {
    const int b = blockIdx.x;
    const int t = threadIdx.x;
    uint16_t* xt = (uint16_t*)ws;
    uint16_t* wt = (uint16_t*)(ws + WT_OFF);

    if (b < XBLK) {
        // 64 pixels per block; thread: pixel = t>>2, ic chunk q = t&3 (16 ic each)
        const int n  = b / (PIX / 64);
        const int p0 = (b - n * (PIX / 64)) * 64;
        const int px = t >> 2;
        const int q  = t & 3;
        const float* src = x + ((size_t)n * ICN + q * 16) * PIX + p0 + px;
        float v[16];
#pragma unroll
        for (int i = 0; i < 16; ++i) v[i] = src[(size_t)i * PIX];
        uint4 u0 = make_uint4(pk2(v[0], v[1]),  pk2(v[2], v[3]),
                              pk2(v[4], v[5]),  pk2(v[6], v[7]));
        uint4 u1 = make_uint4(pk2(v[8], v[9]),  pk2(v[10], v[11]),
                              pk2(v[12], v[13]), pk2(v[14], v[15]));
        char* dst = (char*)xt + ((size_t)(n * PIX + p0 + px)) * 128 + q * 32;
        *(uint4*)dst        = u0;
        *(uint4*)(dst + 16) = u1;
    } else {
        const int wb = b - XBLK;
#pragma unroll
        for (int k = 0; k < 4; ++k) {
            int wi = wb * 1024 + k * 256 + t;          // [0, 73728)
            int r  = wi >> 13;
            int oc = (wi >> 6) & 127;
            int ic = wi & 63;
            wt[wi] = (uint16_t)rne_lo(w[oc * 576 + ic * 9 + r]);
        }
        if (wb == 0 && t < 8) ((uint4*)(ws + ZG_OFF))[t] = make_uint4(0, 0, 0, 0);
    }
}

// ---------------- main conv ----------------
__global__ void __launch_bounds__(256)
conv_mfma(const uint8_t* __restrict__ ws, const float* __restrict__ bias,
          float* __restrict__ out) {
    __shared__ uint16_t As[8192];   // [oc 0..127][ic chunk swizzled] 128B rows
    __shared__ uint16_t Xs[8192];   // [px 0..127][ic chunk swizzled] 128B rows

    const char* xt = (const char*)ws;
    const char* wt = (const char*)(ws + WT_OFF);
    const char* zg = (const char*)(ws + ZG_OFF);

    const int t = threadIdx.x;
    // Bijective XCD-chunked swizzle: XCD k (blockIdx%8) gets contiguous tile ids
    // [k*196, (k+1)*196) -> 2 images per XCD -> 3.2MB xt slice fits 4MB L2.
    const int b = (blockIdx.x & 7) * (NBLK / 8) + (blockIdx.x >> 3);
    const int n_img = b / PTILES;
    const int p0 = (b - n_img * PTILES) * TILEP;

    const int lane = t & 63;
    const int wave = t >> 6;
    const int lr = lane & 15;
    const int lq = lane >> 4;
    const int oc_base = (wave & 1) * 64;
    const int px_base = (wave >> 1) * 64;

    // ---- staging geometry: slot = r2*256 + t; row = r2*32 + (t>>3); cpos = t&7
    const int rowB = t >> 3;                   // 0..31
    const int cswz = (t & 7) ^ (rowB & 7);     // row&7 == rowB&7 (r2*32 = 0 mod 8)
    int sh[4], sw[4];
    const char* xaddr[4];
#pragma unroll
    for (int r2 = 0; r2 < 4; ++r2) {
        int row = r2 * 32 + rowB;
        int p = p0 + row;
        int hh = p / HW;
        sh[r2] = hh;
        sw[r2] = p - hh * HW;
        xaddr[r2] = xt + ((size_t)(n_img * PIX + p)) * 128 + cswz * 16;
    }
    const char* waddr0 = wt + rowB * 128 + cswz * 16;
    const char* zaddr  = zg + (t & 7) * 16;

    f32x4 acc[4][4];
    {
        f32x4 z = {0.f, 0.f, 0.f, 0.f};
#pragma unroll
        for (int i = 0; i < 4; ++i)
#pragma unroll
            for (int j = 0; j < 4; ++j) acc[i][j] = z;
    }

#pragma unroll
    for (int tap = 0; tap < 9; ++tap) {
        const int dy = tap / 3 - 1;
        const int dx = tap - (tap / 3) * 3 - 1;
        const int toff = (dy * HW + dx) * 128;

        __syncthreads();   // all waves done reading previous tap's LDS

        // weights -> As
#pragma unroll
        for (int r2 = 0; r2 < 4; ++r2)
            load_lds16(waddr0 + tap * 16384 + r2 * 4096,
                       (char*)As + r2 * 4096 + wave * 1024);
        // x -> Xs (invalid rows redirected to zero block)
#pragma unroll
        for (int r2 = 0; r2 < 4; ++r2) {
            int hh = sh[r2] + dy;
            int wwp = sw[r2] + dx;
            bool ok = ((unsigned)hh < HW) & ((unsigned)wwp < HW);
            const char* gp = ok ? (xaddr[r2] + toff) : zaddr;
            load_lds16(gp, (char*)Xs + r2 * 4096 + wave * 1024);
        }

        __syncthreads();   // DMA drained (compiler emits vmcnt(0) before barrier)

#pragma unroll
        for (int kh = 0; kh < 2; ++kh) {
            bf16x8 a_frag[4], b_frag[4];
            const int cc = kh * 4 + lq;
#pragma unroll
            for (int mi = 0; mi < 4; ++mi) {
                int R = oc_base + mi * 16 + lr;
                a_frag[mi] = *(const bf16x8*)((const char*)As + R * 128 + ((cc ^ (R & 7)) * 16));
            }
#pragma unroll
            for (int ni = 0; ni < 4; ++ni) {
                int R = px_base + ni * 16 + lr;
                b_frag[ni] = *(const bf16x8*)((const char*)Xs + R * 128 + ((cc ^ (R & 7)) * 16));
            }
#pragma unroll
            for (int mi = 0; mi < 4; ++mi)
#pragma unroll
                for (int ni = 0; ni < 4; ++ni)
                    acc[mi][ni] = __builtin_amdgcn_mfma_f32_16x16x32_bf16(
                        a_frag[mi], b_frag[ni], acc[mi][ni], 0, 0, 0);
        }
    }

    // ---- epilogue: D col = lane&15 -> pixel, row = lq*4+reg -> oc (validated R1)
#pragma unroll
    for (int mi = 0; mi < 4; ++mi) {
#pragma unroll
        for (int rg = 0; rg < 4; ++rg) {
            const int oc = oc_base + mi * 16 + lq * 4 + rg;
            const float bb = bias[oc];
            float* orow = out + ((size_t)n_img * OCN + oc) * PIX + p0 + px_base + lr;
#pragma unroll
            for (int ni = 0; ni < 4; ++ni)
                orow[ni * 16] = acc[mi][ni][rg] + bb;
        }
    }
}

extern "C" void kernel_launch(void* const* d_in, const int* in_sizes, int n_in,
                              void* d_out, int out_size, void* d_ws, size_t ws_size,
                              hipStream_t stream) {
    const float* x    = (const float*)d_in[0];
    const float* w    = (const float*)d_in[1];
    const float* bias = (const float*)d_in[2];
    float* out = (float*)d_out;
    uint8_t* ws = (uint8_t*)d_ws;   // needs ZG_OFF + 128 = 25,837,696 bytes

    prep<<<XBLK + WBLK, 256, 0, stream>>>(x, w, ws);
    conv_mfma<<<NBLK, 256, 0, stream>>>(ws, bias, out);
}

// Round 5
// 169.970 us; speedup vs baseline: 1.4128x; 1.0078x over previous
//
#include <hip/hip_runtime.h>
#include <stdint.h>

// 3x3 conv s1 p1, NCHW fp32, 64->128 ch, 16x112x112.
// Implicit GEMM on bf16 MFMA with NHWC bf16 x-repack in d_ws:
//   prep:  x (NCHW fp32) -> x_t[(n*12544+p)*64+ic] bf16 ; w -> Wt[tap][oc][ic] bf16 ; 128B zero block
//   conv:  per block 128oc x 128px tile; 9 taps. R5: DOUBLE-BUFFERED per-tap stage
//          (As/Xs 2x16KB each) with counted-vmcnt software pipeline:
//            B1 -> stage(tap+1 -> buf^1) -> s_waitcnt vmcnt(8) -> B2 -> compute(buf)
//          Raw s_barrier (no implicit vmcnt(0) drain); tap t+1's 8 global_load_lds stay in
//          flight across both barriers (T3/T4). Per-thread VMEM in loop = exactly 8/stage, so
//          vmcnt(8) == "tap t landed". sched_barrier(0) fences per methodology rule #18.
// Boundary pixels: per-lane global address redirected to the zero block (no LDS patching).
// XCD-chunked bijective block swizzle kept from R4 (xt slice L2-resident).

#define HW     112
#define PIX    12544
#define ICN    64
#define OCN    128
#define TILEP  128
#define PTILES 98
#define NBLK   1568
#define NIMG   16

#define XT_BYTES   (NIMG * PIX * ICN * 2)          // 25,690,112
#define WT_OFF     XT_BYTES
#define WT_BYTES   (9 * OCN * ICN * 2)             // 147,456
#define ZG_OFF     (WT_OFF + WT_BYTES)             // 128B zero block
#define XBLK       (NIMG * (PIX / 64))             // 3136 transpose blocks
#define WBLK       72                              // 72 * 1024 = 73728 weight elems

typedef __attribute__((ext_vector_type(8))) __bf16 bf16x8;
typedef __attribute__((ext_vector_type(4))) float  f32x4;

__device__ __forceinline__ uint32_t rne_lo(float f) {
    uint32_t u = __builtin_bit_cast(uint32_t, f);
    return (u + 0x7fffu + ((u >> 16) & 1u)) >> 16;
}
__device__ __forceinline__ uint32_t pk2(float a, float b) {
    uint32_t ub = __builtin_bit_cast(uint32_t, b);
    ub = (ub + 0x7fffu + ((ub >> 16) & 1u)) & 0xffff0000u;
    return rne_lo(a) | ub;
}

__device__ __forceinline__ void load_lds16(const void* g, void* l) {
    __builtin_amdgcn_global_load_lds(
        (const __attribute__((address_space(1))) uint32_t*)g,
        (__attribute__((address_space(3))) uint32_t*)l, 16, 0, 0);
}

// ---------------- prep: x transpose+cvt, weight transpose+cvt, zero block ----------------
__global__ void __launch_bounds__(256)
prep(const float* __restrict__ x, const float* __restrict__ w, uint8_t* __restrict__ ws) {
    const int b = blockIdx.x;
    const int t = threadIdx.x;
    uint16_t* xt = (uint16_t*)ws;
    uint16_t* wt = (uint16_t*)(ws + WT_OFF);

    if (b < XBLK) {
        // 64 pixels per block; thread: pixel = t>>2, ic chunk q = t&3 (16 ic each)
        const int n  = b / (PIX / 64);
        const int p0 = (b - n * (PIX / 64)) * 64;
        const int px = t >> 2;
        const int q  = t & 3;
        const float* src = x + ((size_t)n * ICN + q * 16) * PIX + p0 + px;
        float v[16];
#pragma unroll
        for (int i = 0; i < 16; ++i) v[i] = src[(size_t)i * PIX];
        uint4 u0 = make_uint4(pk2(v[0], v[1]),  pk2(v[2], v[3]),
                              pk2(v[4], v[5]),  pk2(v[6], v[7]));
        uint4 u1 = make_uint4(pk2(v[8], v[9]),  pk2(v[10], v[11]),
                              pk2(v[12], v[13]), pk2(v[14], v[15]));
        char* dst = (char*)xt + ((size_t)(n * PIX + p0 + px)) * 128 + q * 32;
        *(uint4*)dst        = u0;
        *(uint4*)(dst + 16) = u1;
    } else {
        const int wb = b - XBLK;
#pragma unroll
        for (int k = 0; k < 4; ++k) {
            int wi = wb * 1024 + k * 256 + t;          // [0, 73728)
            int r  = wi >> 13;
            int oc = (wi >> 6) & 127;
            int ic = wi & 63;
            wt[wi] = (uint16_t)rne_lo(w[oc * 576 + ic * 9 + r]);
        }
        if (wb == 0 && t < 8) ((uint4*)(ws + ZG_OFF))[t] = make_uint4(0, 0, 0, 0);
    }
}

// ---------------- main conv ----------------
__global__ void __launch_bounds__(256)
conv_mfma(const uint8_t* __restrict__ ws, const float* __restrict__ bias,
          float* __restrict__ out) {
    __shared__ uint16_t As[2][8192];   // [buf][oc 0..127][ic chunk swizzled] 128B rows
    __shared__ uint16_t Xs[2][8192];   // [buf][px 0..127][ic chunk swizzled] 128B rows

    const char* xt = (const char*)ws;
    const char* wt = (const char*)(ws + WT_OFF);
    const char* zg = (const char*)(ws + ZG_OFF);

    const int t = threadIdx.x;
    // Bijective XCD-chunked swizzle: XCD k (blockIdx%8) gets contiguous tile ids.
    const int b = (blockIdx.x & 7) * (NBLK / 8) + (blockIdx.x >> 3);
    const int n_img = b / PTILES;
    const int p0 = (b - n_img * PTILES) * TILEP;

    const int lane = t & 63;
    const int wave = t >> 6;
    const int lr = lane & 15;
    const int lq = lane >> 4;
    const int oc_base = (wave & 1) * 64;
    const int px_base = (wave >> 1) * 64;

    // ---- staging geometry: slot = r2*256 + t; row = r2*32 + (t>>3); cpos = t&7
    const int rowB = t >> 3;                   // 0..31
    const int cswz = (t & 7) ^ (rowB & 7);     // row&7 == rowB&7 (r2*32 = 0 mod 8)
    int sh[4], sw[4];
    const char* xaddr[4];
#pragma unroll
    for (int r2 = 0; r2 < 4; ++r2) {
        int row = r2 * 32 + rowB;
        int p = p0 + row;
        int hh = p / HW;
        sh[r2] = hh;
        sw[r2] = p - hh * HW;
        xaddr[r2] = xt + ((size_t)(n_img * PIX + p)) * 128 + cswz * 16;
    }
    const char* waddr0 = wt + rowB * 128 + cswz * 16;
    const char* zaddr  = zg + (t & 7) * 16;

    // stage tap T into buffer bsel: exactly 8 global_load_lds per thread (4 W + 4 X)
    auto stage = [&](int tap, int bsel) {
        const int dy = tap / 3 - 1;
        const int dx = tap - (tap / 3) * 3 - 1;
        const int toff = (dy * HW + dx) * 128;
#pragma unroll
        for (int r2 = 0; r2 < 4; ++r2)
            load_lds16(waddr0 + tap * 16384 + r2 * 4096,
                       (char*)As[bsel] + r2 * 4096 + wave * 1024);
#pragma unroll
        for (int r2 = 0; r2 < 4; ++r2) {
            int hh = sh[r2] + dy;
            int wwp = sw[r2] + dx;
            bool ok = ((unsigned)hh < HW) & ((unsigned)wwp < HW);
            const char* gp = ok ? (xaddr[r2] + toff) : zaddr;
            load_lds16(gp, (char*)Xs[bsel] + r2 * 4096 + wave * 1024);
        }
    };

    f32x4 acc[4][4];
    {
        f32x4 z = {0.f, 0.f, 0.f, 0.f};
#pragma unroll
        for (int i = 0; i < 4; ++i)
#pragma unroll
            for (int j = 0; j < 4; ++j) acc[i][j] = z;
    }

    // prologue: tap 0 -> buf 0 (stays in flight; waited at iteration 0's vmcnt)
    stage(0, 0);

#pragma unroll
    for (int tap = 0; tap < 9; ++tap) {
        // B1: everyone finished reading buf^1 (= compute(tap-1)); safe to overwrite.
        __builtin_amdgcn_sched_barrier(0);
        __builtin_amdgcn_s_barrier();

        if (tap < 8) stage(tap + 1, (tap + 1) & 1);
        __builtin_amdgcn_sched_barrier(0);
        if (tap < 8) asm volatile("s_waitcnt vmcnt(8)" ::: "memory");   // tap's 8 landed
        else         asm volatile("s_waitcnt vmcnt(0)" ::: "memory");   // last tap: drain
        __builtin_amdgcn_sched_barrier(0);

        // B2: all waves' tap data in LDS (each passed its own counted wait).
        __builtin_amdgcn_s_barrier();

        const char* Ab = (const char*)As[tap & 1];
        const char* Xb = (const char*)Xs[tap & 1];
#pragma unroll
        for (int kh = 0; kh < 2; ++kh) {
            bf16x8 a_frag[4], b_frag[4];
            const int cc = kh * 4 + lq;
#pragma unroll
            for (int mi = 0; mi < 4; ++mi) {
                int R = oc_base + mi * 16 + lr;
                a_frag[mi] = *(const bf16x8*)(Ab + R * 128 + ((cc ^ (R & 7)) * 16));
            }
#pragma unroll
            for (int ni = 0; ni < 4; ++ni) {
                int R = px_base + ni * 16 + lr;
                b_frag[ni] = *(const bf16x8*)(Xb + R * 128 + ((cc ^ (R & 7)) * 16));
            }
#pragma unroll
            for (int mi = 0; mi < 4; ++mi)
#pragma unroll
                for (int ni = 0; ni < 4; ++ni)
                    acc[mi][ni] = __builtin_amdgcn_mfma_f32_16x16x32_bf16(
                        a_frag[mi], b_frag[ni], acc[mi][ni], 0, 0, 0);
        }
    }

    // ---- epilogue: D col = lane&15 -> pixel, row = lq*4+reg -> oc (validated R1)
#pragma unroll
    for (int mi = 0; mi < 4; ++mi) {
#pragma unroll
        for (int rg = 0; rg < 4; ++rg) {
            const int oc = oc_base + mi * 16 + lq * 4 + rg;
            const float bb = bias[oc];
            float* orow = out + ((size_t)n_img * OCN + oc) * PIX + p0 + px_base + lr;
#pragma unroll
            for (int ni = 0; ni < 4; ++ni)
                orow[ni * 16] = acc[mi][ni][rg] + bb;
        }
    }
}

extern "C" void kernel_launch(void* const* d_in, const int* in_sizes, int n_in,
                              void* d_out, int out_size, void* d_ws, size_t ws_size,
                              hipStream_t stream) {
    const float* x    = (const float*)d_in[0];
    const float* w    = (const float*)d_in[1];
    const float* bias = (const float*)d_in[2];
    float* out = (float*)d_out;
    uint8_t* ws = (uint8_t*)d_ws;   // needs ZG_OFF + 128 = 25,837,696 bytes

    prep<<<XBLK + WBLK, 256, 0, stream>>>(x, w, ws);
    conv_mfma<<<NBLK, 256, 0, stream>>>(ws, bias, out);
}